// Round 5
// baseline (765.615 us; speedup 1.0000x reference)
//
#include <hip/hip_runtime.h>

#define L_MAX 16
#define NCOL  289   // (L_MAX+1)^2
#define TPB   256   // 4 waves per block, one point per thread

// ---- compile-time prefactor table: F[l][m] = (-1)^m sqrt((2l+1)/(2pi) * (l-m)!/(l+m)!) ----
constexpr double csqrt(double x) {
  double g = x > 1.0 ? x : 1.0;
  for (int i = 0; i < 500; ++i) {
    double n = 0.5 * (g + x / g);
    if (n == g) break;
    g = n;
  }
  return g;
}
constexpr double cfact(int n) { double f = 1.0; for (int i = 2; i <= n; ++i) f *= (double)i; return f; }

struct FTab { float v[L_MAX + 1][L_MAX + 1]; };
constexpr FTab make_ftab() {
  FTab t{};
  for (int l = 0; l <= L_MAX; ++l)
    for (int m = 0; m <= l; ++m) {
      double val = ((m & 1) ? -1.0 : 1.0) *
        csqrt((2.0 * l + 1.0) / (2.0 * 3.14159265358979323846) * cfact(l - m) / cfact(l + m));
      t.v[l][m] = (float)val;
    }
  return t;
}
constexpr FTab FT = make_ftab();
constexpr float INVS2 = 0.70710678118654752440f;

using Arr = float[L_MAX + 1];

// Q-row recurrence: advance rolling state from row L-1 (Qp) / L-2 (Qpp) to row L (cur).
template<int L>
__device__ __forceinline__ void qrow(float z, float r2, Arr& Qp, Arr& Qpp, Arr& cur) {
  constexpr float tl = (float)(2 * L - 1);
  cur[L]     = -tl * Qp[L - 1];
  cur[L - 1] =  tl * z * Qp[L - 1];
#pragma unroll
  for (int m = L - 2; m >= 0; --m)
    cur[m] = (tl * z * Qp[m] - (float)(L + m - 1) * r2 * Qpp[m]) * (1.f / (float)(L - m));
#pragma unroll
  for (int m = 0; m < L; ++m) Qpp[m] = Qp[m];
#pragma unroll
  for (int m = 0; m <= L; ++m) Qp[m] = cur[m];
}

// Emit row L's 2L+1 columns into this thread's LDS row (chunk-relative).
template<int L, int C0, int WP>
__device__ __forceinline__ void emit(float* __restrict__ row, const Arr& cc, const Arr& ss, const Arr& cur) {
  constexpr int base = L * L + L - C0;
  row[base] = FT.v[L][0] * cur[0] * INVS2;
#pragma unroll
  for (int m = 1; m <= L; ++m) {
    const float b = FT.v[L][m] * cur[m];
    row[base - m] = b * ss[m];   // m < 0 columns
    row[base + m] = b * cc[m];   // m > 0 columns
  }
}

template<int L, int L1, int C0, int WP>
__device__ __forceinline__ void lrun(float z, float r2, float* __restrict__ row,
                                     const Arr& cc, const Arr& ss, Arr& Qp, Arr& Qpp, Arr& cur) {
  if constexpr (L == 0) { cur[0] = 1.f; Qp[0] = 1.f; }
  else qrow<L>(z, r2, Qp, Qpp, cur);
  emit<L, C0, WP>(row, cc, ss, cur);
  if constexpr (L < L1) lrun<L + 1, L1, C0, WP>(z, r2, row, cc, ss, Qp, Qpp, cur);
}

// One column-chunk (l = L0..L1): compute into LDS, barrier, coalesced flush, barrier.
template<int L0, int L1>
__device__ __forceinline__ void do_chunk(float* __restrict__ lds, int tid, int nvalid,
                                         float* __restrict__ dst, float z, float r2,
                                         const Arr& cc, const Arr& ss, Arr& Qp, Arr& Qpp, Arr& cur) {
  constexpr int C0 = L0 * L0;
  constexpr int W  = (L1 + 1) * (L1 + 1) - C0;
  constexpr int WP = W | 1;   // odd stride -> scatter writes hit all 32 banks (2 lanes/bank = free)
  lrun<L0, L1, C0, WP>(z, r2, lds + tid * WP, cc, ss, Qp, Qpp, cur);
  __syncthreads();
  const int ndw = nvalid * W;
  for (int i = tid; i < ndw; i += TPB) {
    const int r = i / W;          // W constexpr -> magic-mul
    const int c = i - r * W;
    dst[r * NCOL + C0 + c] = lds[r * WP + c];
  }
  __syncthreads();
}

__global__ __launch_bounds__(TPB, 3)   // 3 blocks/CU (LDS 50176 B each) = 12 waves/CU
void sh_kernel(const float* __restrict__ xyz, float* __restrict__ out, int npts) {
  __shared__ float lds[TPB * 49];   // max padded chunk width = 49
  const int tid = threadIdx.x;
  const long long p0 = (long long)blockIdx.x * TPB;
  const int nvalid = min(TPB, (int)(npts - p0));

  float x = 0.f, y = 0.f, z = 0.f;
  if (tid < nvalid) {
    const long long p = p0 + tid;
    x = xyz[3 * p + 0];
    y = xyz[3 * p + 1];
    z = xyz[3 * p + 2];
  }
  const float r2 = x * x + y * y + z * z;

  Arr cc, ss, Qp, Qpp, cur;
  cc[0] = 1.f; ss[0] = 0.f;
#pragma unroll
  for (int m = 1; m <= L_MAX; ++m) {
    cc[m] = x * cc[m - 1] - y * ss[m - 1];
    ss[m] = x * ss[m - 1] + y * cc[m - 1];
  }

  float* dst = out + (size_t)p0 * NCOL;

  // chunk widths W: 36,45,40,48,27,29,31,33 (padded to <=49) — carries Q state across chunks
  do_chunk< 0,  5>(lds, tid, nvalid, dst, z, r2, cc, ss, Qp, Qpp, cur);
  do_chunk< 6,  8>(lds, tid, nvalid, dst, z, r2, cc, ss, Qp, Qpp, cur);
  do_chunk< 9, 10>(lds, tid, nvalid, dst, z, r2, cc, ss, Qp, Qpp, cur);
  do_chunk<11, 12>(lds, tid, nvalid, dst, z, r2, cc, ss, Qp, Qpp, cur);
  do_chunk<13, 13>(lds, tid, nvalid, dst, z, r2, cc, ss, Qp, Qpp, cur);
  do_chunk<14, 14>(lds, tid, nvalid, dst, z, r2, cc, ss, Qp, Qpp, cur);
  do_chunk<15, 15>(lds, tid, nvalid, dst, z, r2, cc, ss, Qp, Qpp, cur);
  do_chunk<16, 16>(lds, tid, nvalid, dst, z, r2, cc, ss, Qp, Qpp, cur);
}

extern "C" void kernel_launch(void* const* d_in, const int* in_sizes, int n_in,
                              void* d_out, int out_size, void* d_ws, size_t ws_size,
                              hipStream_t stream) {
  const float* xyz = (const float*)d_in[0];
  float* out = (float*)d_out;
  const int npts = in_sizes[0] / 3;
  const int nblocks = (npts + TPB - 1) / TPB;
  sh_kernel<<<nblocks, TPB, 0, stream>>>(xyz, out, npts);
}

// Round 7
// 565.779 us; speedup vs baseline: 1.3532x; 1.3532x over previous
//
#include <hip/hip_runtime.h>

#define L_MAX 16
#define NCOL  289   // (L_MAX+1)^2
#define TPB   256   // 4 waves
#define PPB   64    // points per block; 4 threads cooperate per point

// ---- compile-time prefactor table: F[l][m] = (-1)^m sqrt((2l+1)/(2pi) * (l-m)!/(l+m)!) ----
constexpr double csqrt(double x) {
  double g = x > 1.0 ? x : 1.0;
  for (int i = 0; i < 500; ++i) {
    double n = 0.5 * (g + x / g);
    if (n == g) break;
    g = n;
  }
  return g;
}
constexpr double cfact(int n) { double f = 1.0; for (int i = 2; i <= n; ++i) f *= (double)i; return f; }

struct FTab { float v[L_MAX + 1][L_MAX + 1]; };
constexpr FTab make_ftab() {
  FTab t{};
  for (int l = 0; l <= L_MAX; ++l)
    for (int m = 0; m <= l; ++m) {
      double val = ((m & 1) ? -1.0 : 1.0) *
        csqrt((2.0 * l + 1.0) / (2.0 * 3.14159265358979323846) * cfact(l - m) / cfact(l + m));
      t.v[l][m] = (float)val;
    }
  return t;
}
constexpr FTab FT = make_ftab();
constexpr float INVS2 = 0.70710678118654752440f;

using Arr = float[L_MAX + 1];

// Q-row recurrence: advance rolling state from row L-1 (Qp) / L-2 (Qpp) to row L (cur).
// Arithmetic identical to the reference (and to the round-1 kernel that passed).
template<int L>
__device__ __forceinline__ void qrow(float z, float r2, Arr& Qp, Arr& Qpp, Arr& cur) {
  constexpr float tl = (float)(2 * L - 1);
  cur[L]     = -tl * Qp[L - 1];
  cur[L - 1] =  tl * z * Qp[L - 1];
#pragma unroll
  for (int m = L - 2; m >= 0; --m)
    cur[m] = (tl * z * Qp[m] - (float)(L + m - 1) * r2 * Qpp[m]) * (1.f / (float)(L - m));
#pragma unroll
  for (int m = 0; m < L; ++m) Qpp[m] = Qp[m];
#pragma unroll
  for (int m = 0; m <= L; ++m) Qp[m] = cur[m];
}

// Emit row L's 2L+1 columns into this point's LDS row.
// Active lanes during an emit: 16 (one sub per point) at LDS stride 289 floats;
// 289 % 32 == 1 -> 16 distinct banks -> conflict-free.
template<int L>
__device__ __forceinline__ void emit(float* __restrict__ row, const Arr& cc, const Arr& ss, const Arr& cur) {
  constexpr int base = L * L + L;
  row[base] = FT.v[L][0] * cur[0] * INVS2;
#pragma unroll
  for (int m = 1; m <= L; ++m) {
    const float b = FT.v[L][m] * cur[m];
    row[base - m] = b * ss[m];   // m < 0 columns
    row[base + m] = b * cc[m];   // m > 0 columns
  }
}

template<int L>
__device__ __forceinline__ void lrun(float z, float r2, int sub, float* __restrict__ row,
                                     const Arr& cc, const Arr& ss, Arr& Qp, Arr& Qpp, Arr& cur) {
  if constexpr (L == 0) { cur[0] = 1.f; Qp[0] = 1.f; }
  else qrow<L>(z, r2, Qp, Qpp, cur);
  if (sub == (L & 3)) emit<L>(row, cc, ss, cur);   // masked emit; ownership l%4
  if constexpr (L < L_MAX) lrun<L + 1>(z, r2, sub, row, cc, ss, Qp, Qpp, cur);
}

__global__ __launch_bounds__(TPB, 2)   // 74 KB LDS -> 2 blocks/CU = 8 waves across 4 SIMDs
void sh_kernel(const float* __restrict__ xyz, float* __restrict__ out, int npts) {
  __shared__ __align__(16) float lds[PPB * NCOL];   // 64 rows x 289 cols, linear = global order
  const int tid = threadIdx.x;
  const int pt  = tid >> 2;   // 0..63
  const int sub = tid & 3;    // 4 cooperating threads per point
  const long long p0 = (long long)blockIdx.x * PPB;
  const int nvalid = min(PPB, (int)(npts - p0));

  float x = 0.f, y = 0.f, z = 0.f;
  if (pt < nvalid) {
    const long long p = p0 + pt;
    x = xyz[3 * p + 0];
    y = xyz[3 * p + 1];
    z = xyz[3 * p + 2];
  }
  const float r2 = x * x + y * y + z * z;   // pt >= nvalid lanes: zeros -> finite garbage, never flushed

  Arr cc, ss, Qp, Qpp, cur;
  cc[0] = 1.f; ss[0] = 0.f;
#pragma unroll
  for (int m = 1; m <= L_MAX; ++m) {
    cc[m] = x * cc[m - 1] - y * ss[m - 1];
    ss[m] = x * ss[m - 1] + y * cc[m - 1];
  }

  // recurrence uniform across all lanes (4x redundant); emits masked by sub
  lrun<0>(z, r2, sub, &lds[pt * NCOL], cc, ss, Qp, Qpp, cur);

  __syncthreads();

  // contiguous, 64B-aligned float4 stream-out (block base = blockIdx*73984 B, 73984 % 64 == 0)
  float* dst = out + (size_t)p0 * NCOL;
  const int ndw = nvalid * NCOL;
  const int n4  = ndw >> 2;
  const float4* s4 = reinterpret_cast<const float4*>(lds);
  float4*       d4 = reinterpret_cast<float4*>(dst);
  for (int k = tid; k < n4; k += TPB) d4[k] = s4[k];
  for (int i = (n4 << 2) + tid; i < ndw; i += TPB) dst[i] = lds[i];  // generic tail (empty here)
}

extern "C" void kernel_launch(void* const* d_in, const int* in_sizes, int n_in,
                              void* d_out, int out_size, void* d_ws, size_t ws_size,
                              hipStream_t stream) {
  const float* xyz = (const float*)d_in[0];
  float* out = (float*)d_out;
  const int npts = in_sizes[0] / 3;
  const int nblocks = (npts + PPB - 1) / PPB;
  sh_kernel<<<nblocks, TPB, 0, stream>>>(xyz, out, npts);
}